// Round 7
// baseline (643.149 us; speedup 1.0000x reference)
//
#include <hip/hip_runtime.h>

using v8s = __attribute__((ext_vector_type(8))) short;          // 8 bf16 MFMA frag
using v4f = __attribute__((ext_vector_type(4))) float;          // MFMA acc
using v4u = __attribute__((ext_vector_type(4))) unsigned short; // 8B packed
using v8u = __attribute__((ext_vector_type(8))) unsigned short; // 16B copy

// fp32 -> bf16 RNE
__device__ __forceinline__ unsigned short f2b(float x) {
  unsigned int u = __builtin_bit_cast(unsigned int, x);
  return (unsigned short)((u + 0x7FFFu + ((u >> 16) & 1u)) >> 16);
}

// async global -> LDS, 16 bytes per lane (global_load_lds_dwordx4)
__device__ __forceinline__ void gl_lds16(const unsigned short* g, unsigned short* l) {
  __builtin_amdgcn_global_load_lds(
      (const __attribute__((address_space(1))) unsigned int*)g,
      (__attribute__((address_space(3))) unsigned int*)l, 16, 0, 0);
}

// ---------------------------------------------------------------------------
// f32 -> bf16 bulk convert, 8 elems/thread
// ---------------------------------------------------------------------------
__global__ void cvt_kernel(const float* __restrict__ src,
                           unsigned short* __restrict__ dst, int n8) {
  int i = blockIdx.x * 256 + threadIdx.x;
  if (i >= n8) return;
  const float* p = src + (size_t)i * 8;
  float4 a = *(const float4*)p;
  float4 b = *(const float4*)(p + 4);
  v8u o = {f2b(a.x), f2b(a.y), f2b(a.z), f2b(a.w),
           f2b(b.x), f2b(b.y), f2b(b.z), f2b(b.w)};
  *(v8u*)(dst + (size_t)i * 8) = o;
}

// ---------------------------------------------------------------------------
// Pure-bf16 GEMM, m97 recipe: C[m,n] = sum_k A[m,k]*Bw[n,k], 128x128 tile,
// BK=32, 256 thr (4 waves 2x2), global_load_lds width-16 async staging.
// MODE 0: plain store (f32 if OF else bf16). MODE 1 (QKV): cols<1536 -> C
// (bf16, ldc=1536); cols>=1536 (V third) -> VT[(b*3+h)*256+d][2048] transposed.
// ---------------------------------------------------------------------------
template <int MODE, bool OF>
__global__ __launch_bounds__(256, 2)
void gemm_async_kernel(const unsigned short* __restrict__ A,
                       const unsigned short* __restrict__ Bw,
                       void* __restrict__ Cv, unsigned short* __restrict__ VT,
                       int K, int ldc) {
  __shared__ unsigned short As[4096];  // 128 x 32 bf16
  __shared__ unsigned short Bs[4096];

  const int t    = threadIdx.x;
  const int ln   = t & 63;
  const int wv   = t >> 6;
  const int quad = ln >> 4;
  const int L    = ln & 15;
  const int wm   = (wv >> 1) * 64;
  const int wn   = (wv & 1) * 64;
  const long m0  = (long)blockIdx.y * 128;
  const long n0  = (long)blockIdx.x * 128;

  v4f acc[4][4];
#pragma unroll
  for (int i = 0; i < 4; i++)
#pragma unroll
    for (int j = 0; j < 4; j++) acc[i][j] = (v4f){0.f, 0.f, 0.f, 0.f};

  // staging: lane t covers LDS row t>>2 (and +64), k-cols (t&3)*8..+7
  // As[t*8] == As[(t>>2)*32 + (t&3)*8] -> per-lane LDS addr = base + lane*16B
  const int ar = t >> 2;
  const int ac = (t & 3) * 8;
  const unsigned short* Ag = A + (m0 + ar) * (long)K + ac;
  const unsigned short* Bg = Bw + (n0 + ar) * (long)K + ac;
  unsigned short* la = &As[t * 8];
  unsigned short* lb = &Bs[t * 8];
  const long rowskip = 64L * K;

  for (int k0 = 0; k0 < K; k0 += 32) {
    gl_lds16(Ag + k0, la);
    gl_lds16(Ag + rowskip + k0, la + 2048);
    gl_lds16(Bg + k0, lb);
    gl_lds16(Bg + rowskip + k0, lb + 2048);
    __syncthreads();  // compiler drains vmcnt before s_barrier

    v8s af[4], bfr[4];
#pragma unroll
    for (int i = 0; i < 4; i++)
      af[i] = *(const v8s*)(&As[(wm + i * 16 + L) * 32 + quad * 8]);
#pragma unroll
    for (int j = 0; j < 4; j++)
      bfr[j] = *(const v8s*)(&Bs[(wn + j * 16 + L) * 32 + quad * 8]);
#pragma unroll
    for (int i = 0; i < 4; i++)
#pragma unroll
      for (int j = 0; j < 4; j++)
        acc[i][j] = __builtin_amdgcn_mfma_f32_16x16x32_bf16(af[i], bfr[j], acc[i][j], 0, 0, 0);
    __syncthreads();  // all reads done before next iteration's async writes
  }

  if (MODE == 0 || n0 < 1536) {
#pragma unroll
    for (int i = 0; i < 4; i++)
#pragma unroll
      for (int j = 0; j < 4; j++)
#pragma unroll
        for (int r = 0; r < 4; r++) {
          long row = m0 + wm + i * 16 + quad * 4 + r;
          long col = n0 + wn + j * 16 + L;
          if (OF) ((float*)Cv)[row * ldc + col] = acc[i][j][r];
          else    ((unsigned short*)Cv)[row * ldc + col] = f2b(acc[i][j][r]);
        }
  } else {
    // V third: write transposed VT[(b*3+h)*256 + d][token] (bf16)
#pragma unroll
    for (int i = 0; i < 4; i++)
#pragma unroll
      for (int j = 0; j < 4; j++) {
        int colp   = (int)(n0 + wn + j * 16 + L) - 1536;  // 0..767
        int h      = colp >> 8;
        int d      = colp & 255;
        long token = m0 + wm + i * 16 + quad * 4;
        int b  = (int)(token >> 11);
        int tk = (int)(token & 2047);
        v4u val = {f2b(acc[i][j][0]), f2b(acc[i][j][1]), f2b(acc[i][j][2]), f2b(acc[i][j][3])};
        *(v4u*)(&VT[((long)(b * 3 + h) * 256 + d) * 2048 + tk]) = val;
      }
  }
}

// ---------------------------------------------------------------------------
// Barrier-free causal flash attention. One 64-thread block = one wave = one
// 16-row q-strip of one (b,h). K and V fragments loaded DIRECTLY from global
// (K rows are contiguous; VT transposed makes PV B-frags contiguous) -> no
// LDS staging, no __syncthreads anywhere. Only P transposes through LDS.
// Grid (12 bh, 128 strips), heavy strips dispatched first.
// ---------------------------------------------------------------------------
__global__ __launch_bounds__(64, 2)
void attn_kernel(const unsigned short* __restrict__ QK,
                 const unsigned short* __restrict__ VT,
                 unsigned short* __restrict__ Out) {
  __shared__ unsigned short Ps[16 * 40];  // [q 16][key 32 + pad 8]

  const int t    = threadIdx.x;
  const int quad = t >> 4;
  const int L    = t & 15;

  const int bh   = (int)blockIdx.x;
  const int qi   = 127 - (int)blockIdx.y;  // heavy strips first
  const int b    = bh / 3, h = bh % 3;
  const int qrow = qi * 16;
  const long tokbase = (long)b * 2048;

  // Q fragments (A-layout): qf[kc] = Q[qrow+L][kc*32 + quad*8 + 0..7]
  v8s qf[8];
  {
    const unsigned short* Qb = QK + (tokbase + qrow + L) * 1536 + h * 256 + quad * 8;
#pragma unroll
    for (int kc = 0; kc < 8; kc++) qf[kc] = *(const v8s*)(Qb + kc * 32);
  }

  v4f o[16];
#pragma unroll
  for (int dt = 0; dt < 16; dt++) o[dt] = (v4f){0.f, 0.f, 0.f, 0.f};
  float mrow[4] = {-1e9f, -1e9f, -1e9f, -1e9f};
  float lrow[4] = {0.f, 0.f, 0.f, 0.f};

  const unsigned short* Kg = QK + tokbase * 1536 + 768 + h * 256 + quad * 8;
  const unsigned short* Vg = VT + ((long)bh * 256 + L) * 2048 + quad * 8;

  const int nkt = (qrow >> 5) + 1;  // exactly the tiles this strip needs
  for (int kt = 0; kt < nkt; kt++) {
    // ---- S = Q K^T (B-frags direct from global: key rows kt*32+L, +16) ----
    const unsigned short* pK = Kg + (long)(kt * 32 + L) * 1536;
    v4f s0 = (v4f){0.f, 0.f, 0.f, 0.f}, s1 = s0;
#pragma unroll
    for (int kc = 0; kc < 8; kc++) {
      v8s k0 = *(const v8s*)(pK + kc * 32);
      v8s k1 = *(const v8s*)(pK + 16 * 1536 + kc * 32);
      s0 = __builtin_amdgcn_mfma_f32_16x16x32_bf16(qf[kc], k0, s0, 0, 0, 0);
      s1 = __builtin_amdgcn_mfma_f32_16x16x32_bf16(qf[kc], k1, s1, 0, 0, 0);
    }
    // ---- online softmax (rows quad*4+r across the 16 lanes of this quad) ----
    float al[4], p0[4], p1[4];
#pragma unroll
    for (int r = 0; r < 4; r++) {
      int row = qrow + quad * 4 + r;
      int c0  = kt * 32 + L;
      float v0 = (c0 <= row) ? s0[r] * 0.0625f : -1e9f;
      float v1 = (c0 + 16 <= row) ? s1[r] * 0.0625f : -1e9f;
      float mx = fmaxf(v0, v1);
      mx = fmaxf(mx, __shfl_xor(mx, 1));
      mx = fmaxf(mx, __shfl_xor(mx, 2));
      mx = fmaxf(mx, __shfl_xor(mx, 4));
      mx = fmaxf(mx, __shfl_xor(mx, 8));
      float mn = fmaxf(mrow[r], mx);
      float a  = __expf(mrow[r] - mn);
      float e0 = __expf(v0 - mn);
      float e1 = __expf(v1 - mn);
      float sm = e0 + e1;
      sm += __shfl_xor(sm, 1);
      sm += __shfl_xor(sm, 2);
      sm += __shfl_xor(sm, 4);
      sm += __shfl_xor(sm, 8);
      mrow[r] = mn;
      lrow[r] = lrow[r] * a + sm;
      al[r] = a; p0[r] = e0; p1[r] = e1;
    }
#pragma unroll
    for (int dt = 0; dt < 16; dt++)
#pragma unroll
      for (int r = 0; r < 4; r++) o[dt][r] *= al[r];
    // ---- P: C-layout -> LDS -> A-layout (wave-private, no barrier) ----
    unsigned short* Pw = &Ps[(quad * 4) * 40 + L];
#pragma unroll
    for (int r = 0; r < 4; r++) {
      Pw[r * 40]      = f2b(p0[r]);
      Pw[r * 40 + 16] = f2b(p1[r]);
    }
    __threadfence_block();
    v8s pf = *(const v8s*)(&Ps[L * 40 + quad * 8]);
    // ---- O += P V (B-frags direct from transposed VT, contiguous) ----
    const unsigned short* pV = Vg + kt * 32;
#pragma unroll
    for (int dt = 0; dt < 16; dt++) {
      v8s vf = *(const v8s*)(pV + (long)dt * 16 * 2048);
      o[dt] = __builtin_amdgcn_mfma_f32_16x16x32_bf16(pf, vf, o[dt], 0, 0, 0);
    }
  }

  float inv[4];
#pragma unroll
  for (int r = 0; r < 4; r++) inv[r] = 1.0f / fmaxf(lrow[r], 1e-20f);
#pragma unroll
  for (int dt = 0; dt < 16; dt++)
#pragma unroll
    for (int r = 0; r < 4; r++) {
      long row = tokbase + qrow + quad * 4 + r;
      Out[row * 768 + h * 256 + dt * 16 + L] = f2b(o[dt][r] * inv[r]);
    }
}

// ---------------------------------------------------------------------------
extern "C" void kernel_launch(void* const* d_in, const int* in_sizes, int n_in,
                              void* d_out, int out_size, void* d_ws, size_t ws_size,
                              hipStream_t stream) {
  const float* X     = (const float*)d_in[0];  // [4,2048,768] f32
  const float* Wqkv  = (const float*)d_in[1];  // [2304,768]   f32
  const float* Wproj = (const float*)d_in[2];  // [768,768]    f32
  float* out = (float*)d_out;                  // [4,2048,768] f32

  char* ws = (char*)d_ws;
  size_t off = 0;
  unsigned short* QKb = (unsigned short*)(ws + off); off += (size_t)8192 * 1536 * 2;  // 25.2 MB
  unsigned short* VTb = (unsigned short*)(ws + off); off += (size_t)3072 * 2048 * 2;  // 12.6 MB
  // Xb and AOb alias: Xb is dead after GEMM1; AOb written by attn afterwards
  unsigned short* Xb  = (unsigned short*)(ws + off);
  unsigned short* AOb = (unsigned short*)(ws + off); off += (size_t)8192 * 768 * 2;   // 12.6 MB
  unsigned short* Wqb = (unsigned short*)(ws + off); off += (size_t)2304 * 768 * 2;   //  3.5 MB
  unsigned short* Wpb = (unsigned short*)(ws + off); off += (size_t)768 * 768 * 2;    //  1.2 MB

  dim3 blk(256, 1, 1);
  // 0) one-time f32 -> bf16 conversions
  cvt_kernel<<<dim3(3072, 1, 1), blk, 0, stream>>>(X, Xb, 786432);
  cvt_kernel<<<dim3(864, 1, 1), blk, 0, stream>>>(Wqkv, Wqb, 221184);
  cvt_kernel<<<dim3(288, 1, 1), blk, 0, stream>>>(Wproj, Wpb, 73728);
  // 1) QKV projection, async-staged bf16 GEMM (V stored transposed)
  gemm_async_kernel<1, false><<<dim3(18, 64, 1), blk, 0, stream>>>(
      Xb, Wqb, QKb, VTb, 768, 1536);
  // 2) barrier-free causal flash attention
  attn_kernel<<<dim3(12, 128, 1), dim3(64, 1, 1), 0, stream>>>(QKb, VTb, AOb);
  // 3) output projection, f32 store
  gemm_async_kernel<0, true><<<dim3(6, 64, 1), blk, 0, stream>>>(
      AOb, Wpb, out, (unsigned short*)nullptr, 768, 768);
}

// Round 8
// 314.087 us; speedup vs baseline: 2.0477x; 2.0477x over previous
//
#include <hip/hip_runtime.h>

using v8s = __attribute__((ext_vector_type(8))) short;          // 8 bf16 MFMA frag
using v4f = __attribute__((ext_vector_type(4))) float;          // MFMA acc
using v4u = __attribute__((ext_vector_type(4))) unsigned short; // 8B packed
using v8u = __attribute__((ext_vector_type(8))) unsigned short; // 16B copy

// fp32 -> bf16 RNE
__device__ __forceinline__ unsigned short f2b(float x) {
  unsigned int u = __builtin_bit_cast(unsigned int, x);
  return (unsigned short)((u + 0x7FFFu + ((u >> 16) & 1u)) >> 16);
}
// bf16 -> fp32
__device__ __forceinline__ float b2f(unsigned short u) {
  unsigned int v = ((unsigned int)u) << 16;
  return __builtin_bit_cast(float, v);
}

// async global -> LDS, 16 bytes per lane (global_load_lds_dwordx4)
__device__ __forceinline__ void gl_lds16(const unsigned short* g, unsigned short* l) {
  __builtin_amdgcn_global_load_lds(
      (const __attribute__((address_space(1))) unsigned int*)g,
      (__attribute__((address_space(3))) unsigned int*)l, 16, 0, 0);
}

// ---------------------------------------------------------------------------
// f32 -> bf16 bulk convert, 8 elems/thread
// ---------------------------------------------------------------------------
__global__ void cvt_kernel(const float* __restrict__ src,
                           unsigned short* __restrict__ dst, int n8) {
  int i = blockIdx.x * 256 + threadIdx.x;
  if (i >= n8) return;
  const float* p = src + (size_t)i * 8;
  float4 a = *(const float4*)p;
  float4 b = *(const float4*)(p + 4);
  v8u o = {f2b(a.x), f2b(a.y), f2b(a.z), f2b(a.w),
           f2b(b.x), f2b(b.y), f2b(b.z), f2b(b.w)};
  *(v8u*)(dst + (size_t)i * 8) = o;
}

// ---------------------------------------------------------------------------
// Pure-bf16 GEMM, m97 recipe (validated R7): 128x128 tile, BK=32, async staging.
// MODE 1 (QKV): cols<1536 -> C bf16 (ldc=1536); cols>=1536 -> VT transposed.
// MODE 0: plain store (f32 if OF).
// ---------------------------------------------------------------------------
template <int MODE, bool OF>
__global__ __launch_bounds__(256, 2)
void gemm_async_kernel(const unsigned short* __restrict__ A,
                       const unsigned short* __restrict__ Bw,
                       void* __restrict__ Cv, unsigned short* __restrict__ VT,
                       int K, int ldc) {
  __shared__ unsigned short As[4096];
  __shared__ unsigned short Bs[4096];

  const int t    = threadIdx.x;
  const int ln   = t & 63;
  const int wv   = t >> 6;
  const int quad = ln >> 4;
  const int L    = ln & 15;
  const int wm   = (wv >> 1) * 64;
  const int wn   = (wv & 1) * 64;
  const long m0  = (long)blockIdx.y * 128;
  const long n0  = (long)blockIdx.x * 128;

  v4f acc[4][4];
#pragma unroll
  for (int i = 0; i < 4; i++)
#pragma unroll
    for (int j = 0; j < 4; j++) acc[i][j] = (v4f){0.f, 0.f, 0.f, 0.f};

  const int ar = t >> 2;
  const int ac = (t & 3) * 8;
  const unsigned short* Ag = A + (m0 + ar) * (long)K + ac;
  const unsigned short* Bg = Bw + (n0 + ar) * (long)K + ac;
  unsigned short* la = &As[t * 8];
  unsigned short* lb = &Bs[t * 8];
  const long rowskip = 64L * K;

  for (int k0 = 0; k0 < K; k0 += 32) {
    gl_lds16(Ag + k0, la);
    gl_lds16(Ag + rowskip + k0, la + 2048);
    gl_lds16(Bg + k0, lb);
    gl_lds16(Bg + rowskip + k0, lb + 2048);
    __syncthreads();

    v8s af[4], bfr[4];
#pragma unroll
    for (int i = 0; i < 4; i++)
      af[i] = *(const v8s*)(&As[(wm + i * 16 + L) * 32 + quad * 8]);
#pragma unroll
    for (int j = 0; j < 4; j++)
      bfr[j] = *(const v8s*)(&Bs[(wn + j * 16 + L) * 32 + quad * 8]);
#pragma unroll
    for (int i = 0; i < 4; i++)
#pragma unroll
      for (int j = 0; j < 4; j++)
        acc[i][j] = __builtin_amdgcn_mfma_f32_16x16x32_bf16(af[i], bfr[j], acc[i][j], 0, 0, 0);
    __syncthreads();
  }

  if (MODE == 0 || n0 < 1536) {
#pragma unroll
    for (int i = 0; i < 4; i++)
#pragma unroll
      for (int j = 0; j < 4; j++)
#pragma unroll
        for (int r = 0; r < 4; r++) {
          long row = m0 + wm + i * 16 + quad * 4 + r;
          long col = n0 + wn + j * 16 + L;
          if (OF) ((float*)Cv)[row * ldc + col] = acc[i][j][r];
          else    ((unsigned short*)Cv)[row * ldc + col] = f2b(acc[i][j][r]);
        }
  } else {
#pragma unroll
    for (int i = 0; i < 4; i++)
#pragma unroll
      for (int j = 0; j < 4; j++) {
        int colp   = (int)(n0 + wn + j * 16 + L) - 1536;
        int h      = colp >> 8;
        int d      = colp & 255;
        long token = m0 + wm + i * 16 + quad * 4;
        int b  = (int)(token >> 11);
        int tk = (int)(token & 2047);
        v4u val = {f2b(acc[i][j][0]), f2b(acc[i][j][1]), f2b(acc[i][j][2]), f2b(acc[i][j][3])};
        *(v4u*)(&VT[((long)(b * 3 + h) * 256 + d) * 2048 + tk]) = val;
      }
  }
}

// ---------------------------------------------------------------------------
// Split-K flash attention partials. Block = (bh, qtile t of 64 rows, 512-key
// chunk c). 4 waves x 16 q-rows, LDS-staged 32-key tiles (round-6 validated
// math). Writes NORMALIZED partial Ohat = O/l (bf16) + per-row m,l (f32).
// blockIdx.x in [0,80): packed (t,c); chunks per t = t/8+1 (causal).
// ---------------------------------------------------------------------------
__global__ __launch_bounds__(256, 2)
void attn_part_kernel(const unsigned short* __restrict__ QK,
                      const unsigned short* __restrict__ VT,
                      unsigned short* __restrict__ Part,
                      float* __restrict__ ML) {
  __shared__ unsigned short Ks[32 * 264];    // [key 32][d 256 + pad 8]
  __shared__ unsigned short VTs[256 * 40];   // [d 256][key 32 + pad 8]
  __shared__ unsigned short Ps[4 * 16 * 40]; // per-wave [q 16][key 32 + pad 8]

  const int tt   = threadIdx.x;
  const int wv   = tt >> 6;
  const int ln   = tt & 63;
  const int quad = ln >> 4;
  const int L    = ln & 15;

  // decode (t, c) from packed blockIdx.x; group g = t/8 has 8*(g+1) blocks
  int rem = (int)blockIdx.x, g = 0;
  while (rem >= 8 * (g + 1)) { rem -= 8 * (g + 1); g++; }
  const int t = 8 * g + rem / (g + 1);
  const int c = rem - (rem / (g + 1)) * (g + 1);

  const int bh   = (int)blockIdx.y;
  const int b    = bh / 3, h = bh % 3;
  const int qrow = t * 64 + wv * 16;
  const long tokbase = (long)b * 2048;
  const long slot = (long)bh * 80 + blockIdx.x;  // dense chunk slot

  v8s qf[8];
  {
    const unsigned short* Qb = QK + (tokbase + qrow + L) * 1536 + h * 256 + quad * 8;
#pragma unroll
    for (int kc = 0; kc < 8; kc++) qf[kc] = *(const v8s*)(Qb + kc * 32);
  }

  v4f o[16];
#pragma unroll
  for (int dt = 0; dt < 16; dt++) o[dt] = (v4f){0.f, 0.f, 0.f, 0.f};
  float mrow[4] = {-1e9f, -1e9f, -1e9f, -1e9f};
  float lrow[4] = {0.f, 0.f, 0.f, 0.f};

  const unsigned short* Kg = QK + tokbase * 1536 + 768 + h * 256;
  const unsigned short* Vg = VT + (long)bh * 256 * 2048;

  const int nkt = min(16, 2 * t + 2 - 16 * c);  // tiles this chunk needs
  for (int kt = 0; kt < nkt; kt++) {
    const int kglob = c * 512 + kt * 32;
    __syncthreads();
#pragma unroll
    for (int p = 0; p < 4; p++) {
      int idx = p * 256 + tt;
      int kn = idx >> 5, kc = idx & 31;
      *(v8u*)(&Ks[kn * 264 + kc * 8]) =
          *(const v8u*)(Kg + (long)(kglob + kn) * 1536 + kc * 8);
      int d = idx >> 2, vc = idx & 3;
      *(v8u*)(&VTs[d * 40 + vc * 8]) =
          *(const v8u*)(Vg + (long)d * 2048 + kglob + vc * 8);
    }
    __syncthreads();

    if (kglob <= qrow) {  // wave-uniform causal guard
      v4f s0 = (v4f){0.f, 0.f, 0.f, 0.f}, s1 = s0;
#pragma unroll
      for (int kc = 0; kc < 8; kc++) {
        v8s kf0 = *(const v8s*)(&Ks[L * 264 + kc * 32 + quad * 8]);
        v8s kf1 = *(const v8s*)(&Ks[(16 + L) * 264 + kc * 32 + quad * 8]);
        s0 = __builtin_amdgcn_mfma_f32_16x16x32_bf16(qf[kc], kf0, s0, 0, 0, 0);
        s1 = __builtin_amdgcn_mfma_f32_16x16x32_bf16(qf[kc], kf1, s1, 0, 0, 0);
      }
      float al[4], p0[4], p1[4];
#pragma unroll
      for (int r = 0; r < 4; r++) {
        int row = qrow + quad * 4 + r;
        int c0  = kglob + L;
        float v0 = (c0 <= row) ? s0[r] * 0.0625f : -1e9f;
        float v1 = (c0 + 16 <= row) ? s1[r] * 0.0625f : -1e9f;
        float mx = fmaxf(v0, v1);
        mx = fmaxf(mx, __shfl_xor(mx, 1));
        mx = fmaxf(mx, __shfl_xor(mx, 2));
        mx = fmaxf(mx, __shfl_xor(mx, 4));
        mx = fmaxf(mx, __shfl_xor(mx, 8));
        float mn = fmaxf(mrow[r], mx);
        float a  = __expf(mrow[r] - mn);
        float e0 = __expf(v0 - mn);
        float e1 = __expf(v1 - mn);
        float sm = e0 + e1;
        sm += __shfl_xor(sm, 1);
        sm += __shfl_xor(sm, 2);
        sm += __shfl_xor(sm, 4);
        sm += __shfl_xor(sm, 8);
        mrow[r] = mn;
        lrow[r] = lrow[r] * a + sm;
        al[r] = a; p0[r] = e0; p1[r] = e1;
      }
#pragma unroll
      for (int dt = 0; dt < 16; dt++)
#pragma unroll
        for (int r = 0; r < 4; r++) o[dt][r] *= al[r];
      unsigned short* Pw = &Ps[wv * 640 + (quad * 4) * 40 + L];
#pragma unroll
      for (int r = 0; r < 4; r++) {
        Pw[r * 40]      = f2b(p0[r]);
        Pw[r * 40 + 16] = f2b(p1[r]);
      }
      __threadfence_block();
      v8s pf = *(const v8s*)(&Ps[wv * 640 + L * 40 + quad * 8]);
#pragma unroll
      for (int dt = 0; dt < 16; dt++) {
        v8s vf = *(const v8s*)(&VTs[(dt * 16 + L) * 40 + quad * 8]);
        o[dt] = __builtin_amdgcn_mfma_f32_16x16x32_bf16(pf, vf, o[dt], 0, 0, 0);
      }
    }
  }

  // epilogue: normalized partial Ohat (bf16) + m,l (f32)
  float inv[4];
#pragma unroll
  for (int r = 0; r < 4; r++) inv[r] = 1.0f / lrow[r];  // l >= 1 (own max in chunk)
  unsigned short* Pb = Part + slot * 16384;  // [64 rows][256 cols]
#pragma unroll
  for (int dt = 0; dt < 16; dt++)
#pragma unroll
    for (int r = 0; r < 4; r++) {
      int rowl = wv * 16 + quad * 4 + r;
      Pb[rowl * 256 + dt * 16 + L] = f2b(o[dt][r] * inv[r]);
    }
  if (L == 0) {
    float* mlb = ML + slot * 128;
#pragma unroll
    for (int r = 0; r < 4; r++) {
      int rowl = wv * 16 + quad * 4 + r;
      mlb[rowl * 2]     = mrow[r];
      mlb[rowl * 2 + 1] = lrow[r];
    }
  }
}

// ---------------------------------------------------------------------------
// Combine <=4 chunk partials per (bh, qtile). Block=(t, bh), 256 thr: thread
// handles row=tid>>2 (64 rows), 64-col segment (tid&3)*64.
// ---------------------------------------------------------------------------
__global__ __launch_bounds__(256, 2)
void attn_reduce_kernel(const unsigned short* __restrict__ Part,
                        const float* __restrict__ ML,
                        unsigned short* __restrict__ Out) {
  const int t  = (int)blockIdx.x;
  const int bh = (int)blockIdx.y;
  const int b  = bh / 3, h = bh % 3;
  const int g  = t >> 3;
  const int off = 4 * g * (g + 1) + (t - 8 * g) * (g + 1);
  const int nch = g + 1;
  const long slot0 = (long)bh * 80 + off;

  const int tid = threadIdx.x;
  const int row = tid >> 2;
  const int cs  = (tid & 3) * 64;

  float mc[4], lc[4];
  float M = -1e30f;
  for (int c = 0; c < nch; c++) {
    const float* mlb = ML + (slot0 + c) * 128 + row * 2;
    mc[c] = mlb[0];
    lc[c] = mlb[1];
    M = fmaxf(M, mc[c]);
  }
  float wn[4], S = 0.f;
  for (int c = 0; c < nch; c++) { wn[c] = __expf(mc[c] - M) * lc[c]; S += wn[c]; }
  const float invS = 1.0f / S;
  for (int c = 0; c < nch; c++) wn[c] *= invS;

  unsigned short* Or = Out + ((long)b * 2048 + t * 64 + row) * 768 + h * 256 + cs;
#pragma unroll
  for (int j = 0; j < 8; j++) {
    float acc[8] = {0.f, 0.f, 0.f, 0.f, 0.f, 0.f, 0.f, 0.f};
    for (int c = 0; c < nch; c++) {
      v8u p = *(const v8u*)(Part + (slot0 + c) * 16384 + row * 256 + cs + j * 8);
#pragma unroll
      for (int e = 0; e < 8; e++) acc[e] += wn[c] * b2f(p[e]);
    }
    v8u ov = {f2b(acc[0]), f2b(acc[1]), f2b(acc[2]), f2b(acc[3]),
              f2b(acc[4]), f2b(acc[5]), f2b(acc[6]), f2b(acc[7])};
    *(v8u*)(Or + j * 8) = ov;
  }
}

// ---------------------------------------------------------------------------
extern "C" void kernel_launch(void* const* d_in, const int* in_sizes, int n_in,
                              void* d_out, int out_size, void* d_ws, size_t ws_size,
                              hipStream_t stream) {
  const float* X     = (const float*)d_in[0];  // [4,2048,768] f32
  const float* Wqkv  = (const float*)d_in[1];  // [2304,768]   f32
  const float* Wproj = (const float*)d_in[2];  // [768,768]    f32
  float* out = (float*)d_out;                  // [4,2048,768] f32

  char* ws = (char*)d_ws;
  size_t off = 0;
  unsigned short* QKb = (unsigned short*)(ws + off); off += (size_t)8192 * 1536 * 2;  // 25.2 MB
  unsigned short* VTb = (unsigned short*)(ws + off); off += (size_t)3072 * 2048 * 2;  // 12.6 MB
  unsigned short* Xb  = (unsigned short*)(ws + off);                                   // aliases AOb
  unsigned short* AOb = (unsigned short*)(ws + off); off += (size_t)8192 * 768 * 2;   // 12.6 MB
  unsigned short* Wqb = (unsigned short*)(ws + off); off += (size_t)2304 * 768 * 2;   //  3.5 MB
  unsigned short* Wpb = (unsigned short*)(ws + off); off += (size_t)768 * 768 * 2;    //  1.2 MB
  unsigned short* Prt = (unsigned short*)(ws + off); off += (size_t)960 * 16384 * 2;  // 31.5 MB
  float*          MLb = (float*)(ws + off);          off += (size_t)960 * 128 * 4;    //  0.5 MB

  dim3 blk(256, 1, 1);
  // 0) one-time f32 -> bf16 conversions
  cvt_kernel<<<dim3(3072, 1, 1), blk, 0, stream>>>(X, Xb, 786432);
  cvt_kernel<<<dim3(864, 1, 1), blk, 0, stream>>>(Wqkv, Wqb, 221184);
  cvt_kernel<<<dim3(288, 1, 1), blk, 0, stream>>>(Wproj, Wpb, 73728);
  // 1) QKV projection (V stored transposed)
  gemm_async_kernel<1, false><<<dim3(18, 64, 1), blk, 0, stream>>>(
      Xb, Wqb, QKb, VTb, 768, 1536);
  // 2a) split-K flash attention partials (960 blocks, 15 waves/CU)
  attn_part_kernel<<<dim3(80, 12, 1), blk, 0, stream>>>(QKb, VTb, Prt, MLb);
  // 2b) combine partials
  attn_reduce_kernel<<<dim3(32, 12, 1), blk, 0, stream>>>(Prt, MLb, AOb);
  // 3) output projection, f32 store
  gemm_async_kernel<0, true><<<dim3(6, 64, 1), blk, 0, stream>>>(
      AOb, Wpb, out, (unsigned short*)nullptr, 768, 768);
}